// Round 14
// baseline (493.658 us; speedup 1.0000x reference)
//
#include <hip/hip_runtime.h>
#include <stdint.h>

// Analog MVM (aihwkit TorchSimulatorTile) for MI355X.
// input_ [8192,4096] f32, weight [4096,4096] f32, out [8192,4096] f32.
//
// R1: JAX partitionable threefry bits = out0 ^ out1.       (passed, 0.31)
// R2: baseline 673 us; GEMM 435 us @ 27% MfmaUtil, 1.0e8 LDS bank conflicts.
// R3: FAILED (2087 us): fused epilogue (128^2, register-starved). Reverted.
// R4: FAILED (1116 us): same-address atomicAdd across 16384 blocks (~650us).
// R5: XCD swizzle: FETCH 366->917 MB (B-panel L2 reuse destroyed). DROPPED.
// R6: both-sides XOR LDS swizzle: conflicts 1.0e8 -> 0, GEMM 445->371 us.
// R7: counted-vmcnt double-buffer (raw s_barrier + vmcnt(8)): GEMM ->340 us.
// R8: 256x256 tile, 512 thr (8 waves 2Mx4N), acc[8][4]: GEMM ->300 us.
// R9: FAILED (GEMM 483): BK=32 4-deep pipeline halved per-phase compute.
// R10: FAILED (GEMM ~600): ADC epilogue fused into 1-block/CU GEMM.
// R11/R13: consolidated best-known: 489 us total (GEMM 296 @ 929 TF).
// R12: FAILED (GEMM 330): phase barriers WITHOUT spread staging = lockstep
//      cost, no new overlap. Template's lever is per-phase gload interleave.
// R14: faithful m201 8-phase port: LDS [parity][half][128][64]; group kt
//      (4 phases) reads parity kt&1, stages kt+1's 4 half-tiles (1/phase,
//      2 gloads/thread) into parity^1 (unread all group). Phase = {4 af
//      ds_read (+8 bg at q0, lgkm(8)); 1 half-tile stage; barrier; lgkm(0)
//      +sched_barrier; setprio(1); 16 MFMA; setprio(0); barrier}. Boundary
//      vmcnt(0)+barrier (safe variant of template's vmcnt(6); staged loads
//      are 96.5% L2-hit and 1-4 phases old -> drain ~25-100 cyc/K-tile).
//      MFMA chain order per acc element unchanged -> bit-identical.

#define MM 8192
#define KK 4096
#define NN 4096
#define TOTAL_OUT ((size_t)MM * (size_t)NN)
#define NT (KK / 64)

typedef __attribute__((ext_vector_type(4))) float f32x4;
typedef __attribute__((ext_vector_type(8))) short bf16x8;
typedef __attribute__((ext_vector_type(8))) unsigned short u16x8;

#define R_IN_F ((float)(2.0 / 254.0))     // DAC grid step (f32 of python double)
#define R_OUT_F ((float)(24.0 / 510.0))   // ADC grid step

struct BmState {
  int viol[8];  // viol[p] != 0  <=>  pass p saw ADC clipping
};

// ---------------- Threefry-2x32-20 (exact JAX) ----------------
__host__ __device__ __forceinline__ uint32_t tf_rotl(uint32_t v, int r) {
  return (v << r) | (v >> (32 - r));
}

__host__ __device__ __forceinline__ void threefry2x32(uint32_t k0, uint32_t k1,
                                                      uint32_t x0, uint32_t x1,
                                                      uint32_t &o0, uint32_t &o1) {
  uint32_t ks2 = k0 ^ k1 ^ 0x1BD11BDAu;
  x0 += k0; x1 += k1;
#define TF_R(r) { x0 += x1; x1 = tf_rotl(x1, r); x1 ^= x0; }
  TF_R(13) TF_R(15) TF_R(26) TF_R(6)
  x0 += k1; x1 += ks2 + 1u;
  TF_R(17) TF_R(29) TF_R(16) TF_R(24)
  x0 += ks2; x1 += k0 + 2u;
  TF_R(13) TF_R(15) TF_R(26) TF_R(6)
  x0 += k0; x1 += k1 + 3u;
  TF_R(17) TF_R(29) TF_R(16) TF_R(24)
  x0 += k1; x1 += ks2 + 4u;
  TF_R(13) TF_R(15) TF_R(26) TF_R(6)
  x0 += ks2; x1 += k0 + 5u;
#undef TF_R
  o0 = x0; o1 = x1;
}

// XLA ErfInv32 (Giles polynomial, log1p form).
__device__ __forceinline__ float erfinv_xla(float x) {
  float w = -log1pf(-x * x);
  float p;
  if (w < 5.0f) {
    w = w - 2.5f;
    p = 2.81022636e-08f;
    p = fmaf(p, w, 3.43273939e-07f);
    p = fmaf(p, w, -3.5233877e-06f);
    p = fmaf(p, w, -4.39150654e-06f);
    p = fmaf(p, w, 0.00021858087f);
    p = fmaf(p, w, -0.00125372503f);
    p = fmaf(p, w, -0.00417768164f);
    p = fmaf(p, w, 0.246640727f);
    p = fmaf(p, w, 1.50140941f);
  } else {
    w = sqrtf(w) - 3.0f;
    p = -0.000200214257f;
    p = fmaf(p, w, 0.000100950558f);
    p = fmaf(p, w, 0.00134934322f);
    p = fmaf(p, w, -0.00367342844f);
    p = fmaf(p, w, 0.00573950773f);
    p = fmaf(p, w, -0.0076224613f);
    p = fmaf(p, w, 0.00943887047f);
    p = fmaf(p, w, 1.00167406f);
    p = fmaf(p, w, 2.83297682f);
  }
  return p * x;
}

// JAX uniform(-0.99999994, 1) -> sqrt(2)*erfinv -> *0.06
__device__ __forceinline__ float noise_from_bits(uint32_t bits) {
  uint32_t fb = (bits >> 9) | 0x3f800000u;
  float f = __uint_as_float(fb) - 1.0f;   // [0,1)
  const float lo = -0.99999994f;          // nextafter(-1,0) f32
  float u = f * 2.0f + lo;
  u = fmaxf(lo, u);
  return 0.06f * (1.41421356f * erfinv_xla(u));
}

__device__ __forceinline__ unsigned short bf16_rne(float f) {
  uint32_t x = __float_as_uint(f);
  x += 0x7fffu + ((x >> 16) & 1u);
  return (unsigned short)(x >> 16);
}

// DAC: x = v*s; t = x/r; k = rint(t) clamped to ±127. Value = k (exact int, bf16-exact).
__device__ __forceinline__ float dac_quant(float v, float s) {
  float x = v * s;
  float t = x / R_IN_F;
  float k = rintf(t);
  return fminf(127.0f, fmaxf(-127.0f, k));
}

__device__ __forceinline__ u16x8 quant8(float4 a, float4 b, float s) {
  u16x8 o;
  o[0] = bf16_rne(dac_quant(a.x, s));
  o[1] = bf16_rne(dac_quant(a.y, s));
  o[2] = bf16_rne(dac_quant(a.z, s));
  o[3] = bf16_rne(dac_quant(a.w, s));
  o[4] = bf16_rne(dac_quant(b.x, s));
  o[5] = bf16_rne(dac_quant(b.y, s));
  o[6] = bf16_rne(dac_quant(b.z, s));
  o[7] = bf16_rne(dac_quant(b.w, s));
  return o;
}

__device__ __forceinline__ u16x8 conv8(float4 a, float4 b) {
  u16x8 o;
  o[0] = bf16_rne(a.x); o[1] = bf16_rne(a.y); o[2] = bf16_rne(a.z); o[3] = bf16_rne(a.w);
  o[4] = bf16_rne(b.x); o[5] = bf16_rne(b.y); o[6] = bf16_rne(b.z); o[7] = bf16_rne(b.w);
  return o;
}

// ADC epilogue math for one element (bit-identical across all call sites).
__device__ __forceinline__ float adc_one(float gval, size_t idx, float sc,
                                         uint32_t fk0, uint32_t fk1, bool &bad) {
  uint32_t w0, w1;
  threefry2x32(fk0, fk1, 0u, (uint32_t)idx, w0, w1);
  float o = R_IN_F * gval + noise_from_bits(w0 ^ w1);
  float q = rintf(o / R_OUT_F) * R_OUT_F;
  float z = o + (q - o);  // straight-through forward value
  bad = bad || (z > 12.0f) || (z < -12.0f);
  z = fminf(12.0f, fmaxf(-12.0f, z));
  return z * sc;
}

// Stub gate: pass p runs only if every earlier pass clipped. Stream order
// guarantees viol[q] (q<p) is final before this kernel starts.
__device__ __forceinline__ bool pass_skipped(const BmState *st, int pass) {
  for (int q = 1; q < pass; ++q)
    if (st->viol[q] == 0) return true;
  return false;
}

// ---------------- kernels ----------------
// Merged prep: blocks [0,8192) = rowmax+quant (row in registers, BmState init
// in block 0); blocks [8192,16384) = weight f32->bf16 convert.
__global__ __launch_bounds__(256) void k_prep(const float *__restrict__ in,
                                              const float *__restrict__ w,
                                              float *__restrict__ nm,
                                              unsigned short *__restrict__ ab,
                                              unsigned short *__restrict__ wb,
                                              BmState *st) {
  const int t = threadIdx.x;
  if (blockIdx.x < MM) {
    if (blockIdx.x == 0 && t == 0) {
      for (int i = 0; i < 8; ++i) st->viol[i] = 0;
    }
    const int row = blockIdx.x;
    const float *r = in + (size_t)row * KK;
    float4 a0 = *(const float4 *)(r + t * 8);
    float4 a1 = *(const float4 *)(r + t * 8 + 4);
    float4 b0 = *(const float4 *)(r + 2048 + t * 8);
    float4 b1 = *(const float4 *)(r + 2048 + t * 8 + 4);
    float m = 0.0f;
    m = fmaxf(m, fmaxf(fmaxf(fabsf(a0.x), fabsf(a0.y)), fmaxf(fabsf(a0.z), fabsf(a0.w))));
    m = fmaxf(m, fmaxf(fmaxf(fabsf(a1.x), fabsf(a1.y)), fmaxf(fabsf(a1.z), fabsf(a1.w))));
    m = fmaxf(m, fmaxf(fmaxf(fabsf(b0.x), fabsf(b0.y)), fmaxf(fabsf(b0.z), fabsf(b0.w))));
    m = fmaxf(m, fmaxf(fmaxf(fabsf(b1.x), fabsf(b1.y)), fmaxf(fabsf(b1.z), fabsf(b1.w))));
#pragma unroll
    for (int off = 32; off > 0; off >>= 1) m = fmaxf(m, __shfl_down(m, off));
    __shared__ float wm[4];
    if ((t & 63) == 0) wm[t >> 6] = m;
    __syncthreads();
    const float mm = fmaxf(fmaxf(wm[0], wm[1]), fmaxf(wm[2], wm[3]));
    const float nmv = (mm <= 0.0f) ? 1.0f : mm;
    if (t == 0) nm[row] = nmv;
    const float s = 1.0f / (nmv * 1.0f);
    unsigned short *o = ab + (size_t)row * KK;
    *(u16x8 *)(o + t * 8) = quant8(a0, a1, s);
    *(u16x8 *)(o + 2048 + t * 8) = quant8(b0, b1, s);
  } else {
    const size_t idx = ((size_t)(blockIdx.x - MM) * 256 + t) * 8;
    float4 a = *(const float4 *)(w + idx);
    float4 b = *(const float4 *)(w + idx + 4);
    *(u16x8 *)(wb + idx) = conv8(a, b);
  }
}

// Fallback (small-ws path only): rowmax + init.
__global__ __launch_bounds__(256) void k_rowmax(const float *__restrict__ in,
                                                float *__restrict__ nm, BmState *st) {
  if (blockIdx.x == 0 && threadIdx.x == 0) {
    for (int i = 0; i < 8; ++i) st->viol[i] = 0;
  }
  const int row = blockIdx.x;
  const float4 *r = (const float4 *)(in + (size_t)row * KK);
  const int t = threadIdx.x;
  float m = 0.0f;
#pragma unroll
  for (int i = 0; i < 4; ++i) {
    float4 v = r[t + i * 256];
    m = fmaxf(m, fmaxf(fmaxf(fabsf(v.x), fabsf(v.y)), fmaxf(fabsf(v.z), fabsf(v.w))));
  }
#pragma unroll
  for (int off = 32; off > 0; off >>= 1) m = fmaxf(m, __shfl_down(m, off));
  __shared__ float wm[4];
  if ((t & 63) == 0) wm[t >> 6] = m;
  __syncthreads();
  if (t == 0) {
    m = fmaxf(fmaxf(wm[0], wm[1]), fmaxf(wm[2], wm[3]));
    nm[row] = (m <= 0.0f) ? 1.0f : m;
  }
}

__device__ __forceinline__ void async16(const void *g, void *l) {
  __builtin_amdgcn_global_load_lds((const __attribute__((address_space(1))) uint32_t *)g,
                                   (__attribute__((address_space(3))) uint32_t *)l,
                                   16, 0, 0);
}

// Pass-1 GEMM, 8-phase (R14). 256x256 tile, BK=64, 512 threads (8 waves
// 2Mx4N), per-wave 128x64 (acc[8][4]). LDS [parity][half][128][64] per
// operand (128 KB). Group kt = 4 phases reading parity kt&1; each phase
// stages one half-tile of kt+1 into parity^1. Both-sides chunk-XOR swizzle
// within each [128][64] half. Boundary vmcnt(0)+barrier per K-tile.
__global__ __launch_bounds__(512, 1) void k_gemm(const unsigned short *__restrict__ A,
                                                 const unsigned short *__restrict__ B,
                                                 float *__restrict__ C) {
  __shared__ unsigned short As[2][2][128 * 64];
  __shared__ unsigned short Bs[2][2][128 * 64];
  const int tid = threadIdx.x;
  const int lane = tid & 63;
  const int wv = tid >> 6;       // 0..7
  const int wr = wv >> 2;        // 0..1  (M half)
  const int wc = wv & 3;         // 0..3  (N quarter)
  const int brow = blockIdx.y * 256;
  const int bcol = blockIdx.x * 256;

  f32x4 acc[8][4];
#pragma unroll
  for (int m = 0; m < 8; ++m)
#pragma unroll
    for (int n = 0; n < 4; ++n) acc[m][n] = (f32x4){0.f, 0.f, 0.f, 0.f};

  // Per-thread staging constants: half-tile = 128 rows x 64 cols = 1024
  // 16B-units; 2 rounds of 512 threads. row = u>>3, phys chunk = u&7,
  // global chunk = (u&7) ^ (row&7)  (both-sides swizzle, LDS dest linear).
  int srow[2], scg[2], sub[2];
#pragma unroll
  for (int i = 0; i < 2; ++i) {
    const int u = i * 512 + tid;
    srow[i] = u >> 3;
    scg[i] = ((u & 7) ^ (srow[i] & 7)) * 8;  // element offset of 16B chunk
    sub[i] = i * 512 + wv * 64;              // wave-uniform LDS unit base
  }
  const unsigned short *gA[2] = {A + (size_t)brow * KK, A + (size_t)(brow + 128) * KK};
  const unsigned short *gB[2] = {B + (size_t)bcol * KK, B + (size_t)(bcol + 128) * KK};

#define SHALF(dst, src, ktile)                                                         \
  {                                                                                    \
    _Pragma("unroll") for (int i_ = 0; i_ < 2; ++i_) {                                 \
      async16((src) + (size_t)srow[i_] * KK + (size_t)(ktile) * 64 + scg[i_],          \
              (char *)(dst) + (size_t)sub[i_] * 16);                                   \
    }                                                                                  \
  }

  // Prologue: K-tile 0 into parity 0 (8 loads), drain, publish.
  SHALF(As[0][0], gA[0], 0)
  SHALF(As[0][1], gA[1], 0)
  SHALF(Bs[0][0], gB[0], 0)
  SHALF(Bs[0][1], gB[1], 0)
  asm volatile("s_waitcnt vmcnt(0)" ::: "memory");
  __builtin_amdgcn_s_barrier();

  const int r16 = lane & 15;
  const int kgc = lane >> 4;        // 16B chunk within kk-half (0..3)
  const int hB = wc >> 1;           // this wave's B half
  const int rB0 = (wc & 1) * 64;    // row base within that half

#pragma unroll 2
  for (int kt = 0; kt < NT; ++kt) {
    const int p = kt & 1;
    bf16x8 bg[2][4];  // [kk-half][n], read at phase 0, held all 4 phases
#pragma unroll
    for (int q = 0; q < 4; ++q) {
      // ds-load this phase's af quadrant (4 x b128); bg too at phase 0 (8 x b128)
      bf16x8 af[2][2];
#pragma unroll
      for (int x = 0; x < 2; ++x)
#pragma unroll
        for (int mm = 0; mm < 2; ++mm) {
          const int ra = (2 * q + mm) * 16 + r16;
          af[x][mm] = *(const bf16x8 *)(&As[p][wr][ra * 64 +
                                                   (((x * 4 + kgc) ^ (ra & 7)) << 3)]);
        }
      if (q == 0) {
#pragma unroll
        for (int x = 0; x < 2; ++x)
#pragma unroll
          for (int n = 0; n < 4; ++n) {
            const int rb = rB0 + n * 16 + r16;
            bg[x][n] = *(const bf16x8 *)(&Bs[p][hB][rb * 64 +
                                                    (((x * 4 + kgc) ^ (rb & 7)) << 3)]);
          }
      }
      // stage one half-tile of kt+1 into parity^1 (unread during this group)
      if (kt + 1 < NT) {
        const int pn = p ^ 1;
        if (q == 0) { SHALF(As[pn][0], gA[0], kt + 1) }
        else if (q == 1) { SHALF(As[pn][1], gA[1], kt + 1) }
        else if (q == 2) { SHALF(Bs[pn][0], gB[0], kt + 1) }
        else { SHALF(Bs[pn][1], gB[1], kt + 1) }
      }
      if (q == 0) asm volatile("s_waitcnt lgkmcnt(8)" ::: "memory");
      __builtin_amdgcn_s_barrier();
      asm volatile("s_waitcnt lgkmcnt(0)" ::: "memory");
      __builtin_amdgcn_sched_barrier(0);  // rule #18: MFMA must not hoist past wait
      __builtin_amdgcn_s_setprio(1);
#pragma unroll
      for (int x = 0; x < 2; ++x)
#pragma unroll
        for (int mm = 0; mm < 2; ++mm)
#pragma unroll
          for (int n = 0; n < 4; ++n)
            acc[2 * q + mm][n] = __builtin_amdgcn_mfma_f32_16x16x32_bf16(
                af[x][mm], bg[x][n], acc[2 * q + mm][n], 0, 0, 0);
      __builtin_amdgcn_s_setprio(0);
      if (q < 3) {
        __builtin_amdgcn_s_barrier();
      } else {
        // K-tile boundary: all of kt+1's staged loads must be landed (across
        // ALL waves) before any wave's phase-0 ds_reads of the next group.
        __builtin_amdgcn_sched_barrier(0);
        asm volatile("s_waitcnt vmcnt(0)" ::: "memory");
        __builtin_amdgcn_s_barrier();
      }
    }
  }
#undef SHALF

  const int c16 = lane & 15;
  const int q4 = (lane >> 4) * 4;
#pragma unroll
  for (int m = 0; m < 8; ++m) {
    const int row = brow + wr * 128 + m * 16 + q4;
#pragma unroll
    for (int n = 0; n < 4; ++n) {
      const int col = bcol + wc * 64 + n * 16 + c16;
      float *cp = C + (size_t)row * NN + col;
      cp[0 * (size_t)NN] = acc[m][n][0];
      cp[1 * (size_t)NN] = acc[m][n][1];
      cp[2 * (size_t)NN] = acc[m][n][2];
      cp[3 * (size_t)NN] = acc[m][n][3];
    }
  }
}

// pass-1 ADC epilogue, high-occupancy (R10 lesson: never fuse into the
// 1-block/CU GEMM).
__global__ __launch_bounds__(256) void k_epi(float *__restrict__ out,
                                             const float *__restrict__ nm,
                                             BmState *__restrict__ st, int pass, float red,
                                             uint32_t fk0, uint32_t fk1) {
  const size_t idx = ((size_t)blockIdx.x * 256 + threadIdx.x) * 8;
  const int row = (int)(idx >> 12);
  const float sc = nm[row] * red;
  float4 a = *(const float4 *)(out + idx);
  float4 b = *(const float4 *)(out + idx + 4);
  float v[8] = {a.x, a.y, a.z, a.w, b.x, b.y, b.z, b.w};
  bool bad = false;
#pragma unroll
  for (int j = 0; j < 8; ++j) v[j] = adc_one(v[j], idx + j, sc, fk0, fk1, bad);
  *(float4 *)(out + idx) = make_float4(v[0], v[1], v[2], v[3]);
  *(float4 *)(out + idx + 4) = make_float4(v[4], v[5], v[6], v[7]);
  unsigned long long vb = __ballot(bad ? 1 : 0);
  if (vb != 0ull && (threadIdx.x & 63) == 0) atomicOr(&st->viol[pass], 1);
}

// Retry pass p (p>=2 stubs exit via the viol chain; p==1 always runs in the
// small-ws path). Self-contained reg-staged GEMM + fused ADC epilogue.
__global__ __launch_bounds__(256) void k_retry(const float *__restrict__ Af,
                                               const float *__restrict__ Bf,
                                               const float *__restrict__ nm, float red,
                                               float *__restrict__ C,
                                               BmState *__restrict__ st, int pass,
                                               uint32_t fk0, uint32_t fk1) {
  if (pass_skipped(st, pass)) return;
  __shared__ unsigned short As[128 * 64];
  __shared__ unsigned short Bs[128 * 64];
  const int tid = threadIdx.x;
  const int lane = tid & 63;
  const int wv = tid >> 6;
  const int wr = wv >> 1, wc = wv & 1;
  const int brow = blockIdx.y * 128;
  const int bcol = blockIdx.x * 128;

  f32x4 acc[4][4];
#pragma unroll
  for (int m = 0; m < 4; ++m)
#pragma unroll
    for (int n = 0; n < 4; ++n) acc[m][n] = (f32x4){0.f, 0.f, 0.f, 0.f};

  float sA[4];
#pragma unroll
  for (int i = 0; i < 4; ++i) {
    int u = i * 256 + tid;
    sA[i] = 1.0f / (nm[brow + (u >> 3)] * red);
  }

  for (int kt = 0; kt < KK; kt += 64) {
#pragma unroll
    for (int i = 0; i < 4; ++i) {
      const int u = i * 256 + tid;
      const int r = u >> 3, k8 = (u & 7) * 8;
      {
        const float *g = Af + (size_t)(brow + r) * KK + kt + k8;
        float4 x = *(const float4 *)g, y = *(const float4 *)(g + 4);
        *(u16x8 *)(As + r * 64 + k8) = quant8(x, y, sA[i]);
      }
      {
        const float *g = Bf + (size_t)(bcol + r) * KK + kt + k8;
        float4 x = *(const float4 *)g, y = *(const float4 *)(g + 4);
        *(u16x8 *)(Bs + r * 64 + k8) = conv8(x, y);
      }
    }
    __syncthreads();

    const int r16 = lane & 15;
    const int kg = (lane >> 4) * 8;
#pragma unroll
    for (int kk = 0; kk < 64; kk += 32) {
      bf16x8 af[4], bg[4];
#pragma unroll
      for (int m = 0; m < 4; ++m)
        af[m] = *(const bf16x8 *)(As + (wr * 64 + m * 16 + r16) * 64 + kk + kg);
#pragma unroll
      for (int n = 0; n < 4; ++n)
        bg[n] = *(const bf16x8 *)(Bs + (wc * 64 + n * 16 + r16) * 64 + kk + kg);
#pragma unroll
      for (int m = 0; m < 4; ++m)
#pragma unroll
        for (int n = 0; n < 4; ++n)
          acc[m][n] = __builtin_amdgcn_mfma_f32_16x16x32_bf16(af[m], bg[n], acc[m][n], 0, 0, 0);
    }
    __syncthreads();
  }

  const int c16 = lane & 15;
  const int q4 = (lane >> 4) * 4;
  bool bad = false;
#pragma unroll
  for (int m = 0; m < 4; ++m) {
    const int row0 = brow + wr * 64 + m * 16 + q4;
#pragma unroll
    for (int j = 0; j < 4; ++j) {
      const int row = row0 + j;
      const float sc = nm[row] * red;
#pragma unroll
      for (int n = 0; n < 4; ++n) {
        const int col = bcol + wc * 64 + n * 16 + c16;
        const size_t idx = (size_t)row * NN + col;
        C[idx] = adc_one(acc[m][n][j], idx, sc, fk0, fk1, bad);
      }
    }
  }
  unsigned long long vb = __ballot(bad ? 1 : 0);
  if (vb != 0ull && (threadIdx.x & 63) == 0) atomicOr(&st->viol[pass], 1);
}

// ---------------- launch ----------------
extern "C" void kernel_launch(void *const *d_in, const int *in_sizes, int n_in,
                              void *d_out, int out_size, void *d_ws, size_t ws_size,
                              hipStream_t stream) {
  const float *input = (const float *)d_in[0];
  const float *weight = (const float *)d_in[1];
  if (n_in >= 2 && in_sizes[0] < in_sizes[1]) {  // defensive: input is the bigger one
    const float *t = input; input = weight; weight = t;
  }
  float *out = (float *)d_out;
  char *ws = (char *)d_ws;
  BmState *st = (BmState *)ws;
  float *nm = (float *)(ws + 4096);
  unsigned short *Ab = (unsigned short *)(ws + 36864);
  unsigned short *Wb = Ab + (size_t)MM * KK;
  const size_t need = 36864 + ((size_t)MM * KK + (size_t)NN * KK) * 2;
  const bool fast = ws_size >= need;

  // fold_in(key(42), p) = threefry((0,42), (0,p)) computed on host
  uint32_t fk[8][2];
  for (int p = 1; p <= 6; ++p) threefry2x32(0u, 42u, 0u, (uint32_t)p, fk[p][0], fk[p][1]);

  if (fast) {
    k_prep<<<dim3(MM + (NN * (size_t)KK) / 2048), dim3(256), 0, stream>>>(
        input, weight, nm, Ab, Wb, st);
    k_gemm<<<dim3(NN / 256, MM / 256), dim3(512), 0, stream>>>(Ab, Wb, out);
    k_epi<<<dim3((int)(TOTAL_OUT / 2048)), dim3(256), 0, stream>>>(out, nm, st, 1, 1.0f,
                                                                   fk[1][0], fk[1][1]);
  } else {
    k_rowmax<<<dim3(MM), dim3(256), 0, stream>>>(input, nm, st);
    k_retry<<<dim3(NN / 128, MM / 128), dim3(256), 0, stream>>>(
        input, weight, nm, 1.0f, out, st, 1, fk[1][0], fk[1][1]);
  }

  float red = 2.0f;
  for (int p = 2; p <= 6; ++p, red *= 2.0f) {
    k_retry<<<dim3(NN / 128, MM / 128), dim3(256), 0, stream>>>(
        input, weight, nm, red, out, st, p, fk[p][0], fk[p][1]);
  }
}

// Round 16
// 489.304 us; speedup vs baseline: 1.0089x; 1.0089x over previous
//
#include <hip/hip_runtime.h>
#include <stdint.h>

// Analog MVM (aihwkit TorchSimulatorTile) for MI355X.
// input_ [8192,4096] f32, weight [4096,4096] f32, out [8192,4096] f32.
//
// R1: JAX partitionable threefry bits = out0 ^ out1.       (passed, 0.31)
// R2: baseline 673 us; GEMM 435 us @ 27% MfmaUtil, 1.0e8 LDS bank conflicts.
// R3: FAILED (2087 us): fused epilogue (128^2, register-starved). Reverted.
// R4: FAILED (1116 us): same-address atomicAdd across 16384 blocks (~650us).
// R5: XCD swizzle: FETCH 366->917 MB (B-panel L2 reuse destroyed). DROPPED.
// R6: both-sides XOR LDS swizzle: conflicts 1.0e8 -> 0, GEMM 445->371 us.
// R7: counted-vmcnt double-buffer (raw s_barrier + vmcnt(8)): GEMM ->340 us.
// R8: 256x256 tile, 512 thr (8 waves 2Mx4N), acc[8][4]: GEMM ->300 us.
// R9: FAILED (GEMM 483): BK=32 4-deep pipeline halved per-phase compute.
// R10: FAILED (GEMM ~600): ADC epilogue fused into 1-block/CU GEMM.
// R11/R13: consolidated best-known: 489 us total (GEMM 296 @ 929 TF).
// R12: FAILED (GEMM 330): lockstep phase barriers, no staging spread.
// R14: safe 8-phase port (vmcnt(0) boundary): NEUTRAL (291 us) — phase
//      split alone adds nothing on this staging scheme.
// R15: FAILED CORRECTNESS (absmax 21.1): counted vmcnt(6) boundary raced —
//      vmcnt(6) retires only each wave's B0 contribution; B1/A0/A1 reads
//      were unprotected. Counted-vmcnt safety is a property of m201's full
//      co-designed template, not of the counter value. GEMM schedule work
//      stopped (4 attempts: 1 race, 2 regressions, 1 neutral).
// R16: R13 byte-exact resubmission — the locked-in best-known kernel.

#define MM 8192
#define KK 4096
#define NN 4096
#define TOTAL_OUT ((size_t)MM * (size_t)NN)
#define NT (KK / 64)

typedef __attribute__((ext_vector_type(4))) float f32x4;
typedef __attribute__((ext_vector_type(8))) short bf16x8;
typedef __attribute__((ext_vector_type(8))) unsigned short u16x8;

#define R_IN_F ((float)(2.0 / 254.0))     // DAC grid step (f32 of python double)
#define R_OUT_F ((float)(24.0 / 510.0))   // ADC grid step

struct BmState {
  int viol[8];  // viol[p] != 0  <=>  pass p saw ADC clipping
};

// ---------------- Threefry-2x32-20 (exact JAX) ----------------
__host__ __device__ __forceinline__ uint32_t tf_rotl(uint32_t v, int r) {
  return (v << r) | (v >> (32 - r));
}

__host__ __device__ __forceinline__ void threefry2x32(uint32_t k0, uint32_t k1,
                                                      uint32_t x0, uint32_t x1,
                                                      uint32_t &o0, uint32_t &o1) {
  uint32_t ks2 = k0 ^ k1 ^ 0x1BD11BDAu;
  x0 += k0; x1 += k1;
#define TF_R(r) { x0 += x1; x1 = tf_rotl(x1, r); x1 ^= x0; }
  TF_R(13) TF_R(15) TF_R(26) TF_R(6)
  x0 += k1; x1 += ks2 + 1u;
  TF_R(17) TF_R(29) TF_R(16) TF_R(24)
  x0 += ks2; x1 += k0 + 2u;
  TF_R(13) TF_R(15) TF_R(26) TF_R(6)
  x0 += k0; x1 += k1 + 3u;
  TF_R(17) TF_R(29) TF_R(16) TF_R(24)
  x0 += k1; x1 += ks2 + 4u;
  TF_R(13) TF_R(15) TF_R(26) TF_R(6)
  x0 += ks2; x1 += k0 + 5u;
#undef TF_R
  o0 = x0; o1 = x1;
}

// XLA ErfInv32 (Giles polynomial, log1p form).
__device__ __forceinline__ float erfinv_xla(float x) {
  float w = -log1pf(-x * x);
  float p;
  if (w < 5.0f) {
    w = w - 2.5f;
    p = 2.81022636e-08f;
    p = fmaf(p, w, 3.43273939e-07f);
    p = fmaf(p, w, -3.5233877e-06f);
    p = fmaf(p, w, -4.39150654e-06f);
    p = fmaf(p, w, 0.00021858087f);
    p = fmaf(p, w, -0.00125372503f);
    p = fmaf(p, w, -0.00417768164f);
    p = fmaf(p, w, 0.246640727f);
    p = fmaf(p, w, 1.50140941f);
  } else {
    w = sqrtf(w) - 3.0f;
    p = -0.000200214257f;
    p = fmaf(p, w, 0.000100950558f);
    p = fmaf(p, w, 0.00134934322f);
    p = fmaf(p, w, -0.00367342844f);
    p = fmaf(p, w, 0.00573950773f);
    p = fmaf(p, w, -0.0076224613f);
    p = fmaf(p, w, 0.00943887047f);
    p = fmaf(p, w, 1.00167406f);
    p = fmaf(p, w, 2.83297682f);
  }
  return p * x;
}

// JAX uniform(-0.99999994, 1) -> sqrt(2)*erfinv -> *0.06
__device__ __forceinline__ float noise_from_bits(uint32_t bits) {
  uint32_t fb = (bits >> 9) | 0x3f800000u;
  float f = __uint_as_float(fb) - 1.0f;   // [0,1)
  const float lo = -0.99999994f;          // nextafter(-1,0) f32
  float u = f * 2.0f + lo;
  u = fmaxf(lo, u);
  return 0.06f * (1.41421356f * erfinv_xla(u));
}

__device__ __forceinline__ unsigned short bf16_rne(float f) {
  uint32_t x = __float_as_uint(f);
  x += 0x7fffu + ((x >> 16) & 1u);
  return (unsigned short)(x >> 16);
}

// DAC: x = v*s; t = x/r; k = rint(t) clamped to ±127. Value = k (exact int, bf16-exact).
__device__ __forceinline__ float dac_quant(float v, float s) {
  float x = v * s;
  float t = x / R_IN_F;
  float k = rintf(t);
  return fminf(127.0f, fmaxf(-127.0f, k));
}

__device__ __forceinline__ u16x8 quant8(float4 a, float4 b, float s) {
  u16x8 o;
  o[0] = bf16_rne(dac_quant(a.x, s));
  o[1] = bf16_rne(dac_quant(a.y, s));
  o[2] = bf16_rne(dac_quant(a.z, s));
  o[3] = bf16_rne(dac_quant(a.w, s));
  o[4] = bf16_rne(dac_quant(b.x, s));
  o[5] = bf16_rne(dac_quant(b.y, s));
  o[6] = bf16_rne(dac_quant(b.z, s));
  o[7] = bf16_rne(dac_quant(b.w, s));
  return o;
}

__device__ __forceinline__ u16x8 conv8(float4 a, float4 b) {
  u16x8 o;
  o[0] = bf16_rne(a.x); o[1] = bf16_rne(a.y); o[2] = bf16_rne(a.z); o[3] = bf16_rne(a.w);
  o[4] = bf16_rne(b.x); o[5] = bf16_rne(b.y); o[6] = bf16_rne(b.z); o[7] = bf16_rne(b.w);
  return o;
}

// ADC epilogue math for one element (bit-identical across all call sites).
__device__ __forceinline__ float adc_one(float gval, size_t idx, float sc,
                                         uint32_t fk0, uint32_t fk1, bool &bad) {
  uint32_t w0, w1;
  threefry2x32(fk0, fk1, 0u, (uint32_t)idx, w0, w1);
  float o = R_IN_F * gval + noise_from_bits(w0 ^ w1);
  float q = rintf(o / R_OUT_F) * R_OUT_F;
  float z = o + (q - o);  // straight-through forward value
  bad = bad || (z > 12.0f) || (z < -12.0f);
  z = fminf(12.0f, fmaxf(-12.0f, z));
  return z * sc;
}

// Stub gate: pass p runs only if every earlier pass clipped. Stream order
// guarantees viol[q] (q<p) is final before this kernel starts.
__device__ __forceinline__ bool pass_skipped(const BmState *st, int pass) {
  for (int q = 1; q < pass; ++q)
    if (st->viol[q] == 0) return true;
  return false;
}

// ---------------- kernels ----------------
// Merged prep: blocks [0,8192) = rowmax+quant (row in registers, BmState init
// in block 0); blocks [8192,16384) = weight f32->bf16 convert.
__global__ __launch_bounds__(256) void k_prep(const float *__restrict__ in,
                                              const float *__restrict__ w,
                                              float *__restrict__ nm,
                                              unsigned short *__restrict__ ab,
                                              unsigned short *__restrict__ wb,
                                              BmState *st) {
  const int t = threadIdx.x;
  if (blockIdx.x < MM) {
    if (blockIdx.x == 0 && t == 0) {
      for (int i = 0; i < 8; ++i) st->viol[i] = 0;
    }
    const int row = blockIdx.x;
    const float *r = in + (size_t)row * KK;
    float4 a0 = *(const float4 *)(r + t * 8);
    float4 a1 = *(const float4 *)(r + t * 8 + 4);
    float4 b0 = *(const float4 *)(r + 2048 + t * 8);
    float4 b1 = *(const float4 *)(r + 2048 + t * 8 + 4);
    float m = 0.0f;
    m = fmaxf(m, fmaxf(fmaxf(fabsf(a0.x), fabsf(a0.y)), fmaxf(fabsf(a0.z), fabsf(a0.w))));
    m = fmaxf(m, fmaxf(fmaxf(fabsf(a1.x), fabsf(a1.y)), fmaxf(fabsf(a1.z), fabsf(a1.w))));
    m = fmaxf(m, fmaxf(fmaxf(fabsf(b0.x), fabsf(b0.y)), fmaxf(fabsf(b0.z), fabsf(b0.w))));
    m = fmaxf(m, fmaxf(fmaxf(fabsf(b1.x), fabsf(b1.y)), fmaxf(fabsf(b1.z), fabsf(b1.w))));
#pragma unroll
    for (int off = 32; off > 0; off >>= 1) m = fmaxf(m, __shfl_down(m, off));
    __shared__ float wm[4];
    if ((t & 63) == 0) wm[t >> 6] = m;
    __syncthreads();
    const float mm = fmaxf(fmaxf(wm[0], wm[1]), fmaxf(wm[2], wm[3]));
    const float nmv = (mm <= 0.0f) ? 1.0f : mm;
    if (t == 0) nm[row] = nmv;
    const float s = 1.0f / (nmv * 1.0f);
    unsigned short *o = ab + (size_t)row * KK;
    *(u16x8 *)(o + t * 8) = quant8(a0, a1, s);
    *(u16x8 *)(o + 2048 + t * 8) = quant8(b0, b1, s);
  } else {
    const size_t idx = ((size_t)(blockIdx.x - MM) * 256 + t) * 8;
    float4 a = *(const float4 *)(w + idx);
    float4 b = *(const float4 *)(w + idx + 4);
    *(u16x8 *)(wb + idx) = conv8(a, b);
  }
}

// Fallback (small-ws path only): rowmax + init.
__global__ __launch_bounds__(256) void k_rowmax(const float *__restrict__ in,
                                                float *__restrict__ nm, BmState *st) {
  if (blockIdx.x == 0 && threadIdx.x == 0) {
    for (int i = 0; i < 8; ++i) st->viol[i] = 0;
  }
  const int row = blockIdx.x;
  const float4 *r = (const float4 *)(in + (size_t)row * KK);
  const int t = threadIdx.x;
  float m = 0.0f;
#pragma unroll
  for (int i = 0; i < 4; ++i) {
    float4 v = r[t + i * 256];
    m = fmaxf(m, fmaxf(fmaxf(fabsf(v.x), fabsf(v.y)), fmaxf(fabsf(v.z), fabsf(v.w))));
  }
#pragma unroll
  for (int off = 32; off > 0; off >>= 1) m = fmaxf(m, __shfl_down(m, off));
  __shared__ float wm[4];
  if ((t & 63) == 0) wm[t >> 6] = m;
  __syncthreads();
  if (t == 0) {
    m = fmaxf(fmaxf(wm[0], wm[1]), fmaxf(wm[2], wm[3]));
    nm[row] = (m <= 0.0f) ? 1.0f : m;
  }
}

__device__ __forceinline__ void async16(const void *g, void *l) {
  __builtin_amdgcn_global_load_lds((const __attribute__((address_space(1))) uint32_t *)g,
                                   (__attribute__((address_space(3))) uint32_t *)l,
                                   16, 0, 0);
}

// Pass-1 GEMM, R8-exact: 256x256 tile, BK=64, 512 threads (8 waves 2Mx4N),
// per-wave 128x64 (acc[8][4]), double-buffered 128 KB LDS, counted-vmcnt
// pipeline (STAGE next -> vmcnt(8) -> raw barrier -> MFMA -> sched_barrier ->
// barrier), both-sides chunk-XOR swizzle. Raw f32 C store; ADC epilogue
// stays in the separate high-occupancy k_epi (R10 lesson).
__global__ __launch_bounds__(512, 1) void k_gemm(const unsigned short *__restrict__ A,
                                                 const unsigned short *__restrict__ B,
                                                 float *__restrict__ C) {
  __shared__ unsigned short As[2][256 * 64];
  __shared__ unsigned short Bs[2][256 * 64];
  const int tid = threadIdx.x;
  const int lane = tid & 63;
  const int wv = tid >> 6;       // 0..7
  const int wr = wv >> 2;        // 0..1  (M half)
  const int wc = wv & 3;         // 0..3  (N quarter)
  const int brow = blockIdx.y * 256;
  const int bcol = blockIdx.x * 256;

  f32x4 acc[8][4];
#pragma unroll
  for (int m = 0; m < 8; ++m)
#pragma unroll
    for (int n = 0; n < 4; ++n) acc[m][n] = (f32x4){0.f, 0.f, 0.f, 0.f};

  // staging indices: round i covers units i*512 + tid (row = unit>>3, 8 chunks/row)
  int sr[4], sk8[4];
#pragma unroll
  for (int i = 0; i < 4; ++i) {
    const int u = i * 512 + tid;
    sr[i] = u >> 3;
    sk8[i] = ((u & 7) ^ (sr[i] & 7)) * 8;  // pre-swizzled global 16B chunk (elems)
  }

#define STAGE(buf, kt)                                                                 \
  {                                                                                    \
    _Pragma("unroll") for (int i = 0; i < 4; ++i) {                                    \
      const int ub = i * 512 + wv * 64; /* wave-uniform LDS unit base */               \
      async16(A + (size_t)(brow + sr[i]) * KK + (kt) * 64 + sk8[i],                    \
              (char *)As[buf] + (size_t)ub * 16);                                      \
      async16(B + (size_t)(bcol + sr[i]) * KK + (kt) * 64 + sk8[i],                    \
              (char *)Bs[buf] + (size_t)ub * 16);                                      \
    }                                                                                  \
  }

  STAGE(0, 0);

  const int r16 = lane & 15;
  const int kg = (lane >> 4) * 8;

#pragma unroll 2
  for (int kt = 0; kt < NT; ++kt) {
    const int cur = kt & 1;
    if (kt + 1 < NT) {
      STAGE(cur ^ 1, kt + 1);
      asm volatile("s_waitcnt vmcnt(8)" ::: "memory");  // current tile landed
    } else {
      asm volatile("s_waitcnt vmcnt(0)" ::: "memory");
    }
    __builtin_amdgcn_s_barrier();  // raw: prefetch loads stay in flight

#pragma unroll
    for (int kk = 0; kk < 64; kk += 32) {
      const int ck = (kk + kg) >> 3;  // logical 16B chunk index
      bf16x8 af[8], bg[4];
#pragma unroll
      for (int m = 0; m < 8; ++m) {
        const int ra = wr * 128 + m * 16 + r16;
        af[m] = *(const bf16x8 *)(As[cur] + ra * 64 + ((ck ^ (ra & 7)) << 3));
      }
#pragma unroll
      for (int n = 0; n < 4; ++n) {
        const int rb = wc * 64 + n * 16 + r16;
        bg[n] = *(const bf16x8 *)(Bs[cur] + rb * 64 + ((ck ^ (rb & 7)) << 3));
      }
#pragma unroll
      for (int m = 0; m < 8; ++m)
#pragma unroll
        for (int n = 0; n < 4; ++n)
          acc[m][n] = __builtin_amdgcn_mfma_f32_16x16x32_bf16(af[m], bg[n], acc[m][n], 0, 0, 0);
    }
    __builtin_amdgcn_sched_barrier(0);  // pin ds_reads before the barrier
    __builtin_amdgcn_s_barrier();       // buf[cur^1] safe to overwrite next iter
  }
#undef STAGE

  const int c16 = lane & 15;
  const int q4 = (lane >> 4) * 4;
#pragma unroll
  for (int m = 0; m < 8; ++m) {
    const int row = brow + wr * 128 + m * 16 + q4;
#pragma unroll
    for (int n = 0; n < 4; ++n) {
      const int col = bcol + wc * 64 + n * 16 + c16;
      float *cp = C + (size_t)row * NN + col;
      cp[0 * (size_t)NN] = acc[m][n][0];
      cp[1 * (size_t)NN] = acc[m][n][1];
      cp[2 * (size_t)NN] = acc[m][n][2];
      cp[3 * (size_t)NN] = acc[m][n][3];
    }
  }
}

// pass-1 ADC epilogue, high-occupancy (R10 lesson: never fuse into the
// 1-block/CU GEMM).
__global__ __launch_bounds__(256) void k_epi(float *__restrict__ out,
                                             const float *__restrict__ nm,
                                             BmState *__restrict__ st, int pass, float red,
                                             uint32_t fk0, uint32_t fk1) {
  const size_t idx = ((size_t)blockIdx.x * 256 + threadIdx.x) * 8;
  const int row = (int)(idx >> 12);
  const float sc = nm[row] * red;
  float4 a = *(const float4 *)(out + idx);
  float4 b = *(const float4 *)(out + idx + 4);
  float v[8] = {a.x, a.y, a.z, a.w, b.x, b.y, b.z, b.w};
  bool bad = false;
#pragma unroll
  for (int j = 0; j < 8; ++j) v[j] = adc_one(v[j], idx + j, sc, fk0, fk1, bad);
  *(float4 *)(out + idx) = make_float4(v[0], v[1], v[2], v[3]);
  *(float4 *)(out + idx + 4) = make_float4(v[4], v[5], v[6], v[7]);
  unsigned long long vb = __ballot(bad ? 1 : 0);
  if (vb != 0ull && (threadIdx.x & 63) == 0) atomicOr(&st->viol[pass], 1);
}

// Retry pass p (p>=2 stubs exit via the viol chain; p==1 always runs in the
// small-ws path). Self-contained reg-staged GEMM + fused ADC epilogue.
__global__ __launch_bounds__(256) void k_retry(const float *__restrict__ Af,
                                               const float *__restrict__ Bf,
                                               const float *__restrict__ nm, float red,
                                               float *__restrict__ C,
                                               BmState *__restrict__ st, int pass,
                                               uint32_t fk0, uint32_t fk1) {
  if (pass_skipped(st, pass)) return;
  __shared__ unsigned short As[128 * 64];
  __shared__ unsigned short Bs[128 * 64];
  const int tid = threadIdx.x;
  const int lane = tid & 63;
  const int wv = tid >> 6;
  const int wr = wv >> 1, wc = wv & 1;
  const int brow = blockIdx.y * 128;
  const int bcol = blockIdx.x * 128;

  f32x4 acc[4][4];
#pragma unroll
  for (int m = 0; m < 4; ++m)
#pragma unroll
    for (int n = 0; n < 4; ++n) acc[m][n] = (f32x4){0.f, 0.f, 0.f, 0.f};

  float sA[4];
#pragma unroll
  for (int i = 0; i < 4; ++i) {
    int u = i * 256 + tid;
    sA[i] = 1.0f / (nm[brow + (u >> 3)] * red);
  }

  for (int kt = 0; kt < KK; kt += 64) {
#pragma unroll
    for (int i = 0; i < 4; ++i) {
      const int u = i * 256 + tid;
      const int r = u >> 3, k8 = (u & 7) * 8;
      {
        const float *g = Af + (size_t)(brow + r) * KK + kt + k8;
        float4 x = *(const float4 *)g, y = *(const float4 *)(g + 4);
        *(u16x8 *)(As + r * 64 + k8) = quant8(x, y, sA[i]);
      }
      {
        const float *g = Bf + (size_t)(bcol + r) * KK + kt + k8;
        float4 x = *(const float4 *)g, y = *(const float4 *)(g + 4);
        *(u16x8 *)(Bs + r * 64 + k8) = conv8(x, y);
      }
    }
    __syncthreads();

    const int r16 = lane & 15;
    const int kg = (lane >> 4) * 8;
#pragma unroll
    for (int kk = 0; kk < 64; kk += 32) {
      bf16x8 af[4], bg[4];
#pragma unroll
      for (int m = 0; m < 4; ++m)
        af[m] = *(const bf16x8 *)(As + (wr * 64 + m * 16 + r16) * 64 + kk + kg);
#pragma unroll
      for (int n = 0; n < 4; ++n)
        bg[n] = *(const bf16x8 *)(Bs + (wc * 64 + n * 16 + r16) * 64 + kk + kg);
#pragma unroll
      for (int m = 0; m < 4; ++m)
#pragma unroll
        for (int n = 0; n < 4; ++n)
          acc[m][n] = __builtin_amdgcn_mfma_f32_16x16x32_bf16(af[m], bg[n], acc[m][n], 0, 0, 0);
    }
    __syncthreads();
  }

  const int c16 = lane & 15;
  const int q4 = (lane >> 4) * 4;
  bool bad = false;
#pragma unroll
  for (int m = 0; m < 4; ++m) {
    const int row0 = brow + wr * 64 + m * 16 + q4;
#pragma unroll
    for (int j = 0; j < 4; ++j) {
      const int row = row0 + j;
      const float sc = nm[row] * red;
#pragma unroll
      for (int n = 0; n < 4; ++n) {
        const int col = bcol + wc * 64 + n * 16 + c16;
        const size_t idx = (size_t)row * NN + col;
        C[idx] = adc_one(acc[m][n][j], idx, sc, fk0, fk1, bad);
      }
    }
  }
  unsigned long long vb = __ballot(bad ? 1 : 0);
  if (vb != 0ull && (threadIdx.x & 63) == 0) atomicOr(&st->viol[pass], 1);
}

// ---------------- launch ----------------
extern "C" void kernel_launch(void *const *d_in, const int *in_sizes, int n_in,
                              void *d_out, int out_size, void *d_ws, size_t ws_size,
                              hipStream_t stream) {
  const float *input = (const float *)d_in[0];
  const float *weight = (const float *)d_in[1];
  if (n_in >= 2 && in_sizes[0] < in_sizes[1]) {  // defensive: input is the bigger one
    const float *t = input; input = weight; weight = t;
  }
  float *out = (float *)d_out;
  char *ws = (char *)d_ws;
  BmState *st = (BmState *)ws;
  float *nm = (float *)(ws + 4096);
  unsigned short *Ab = (unsigned short *)(ws + 36864);
  unsigned short *Wb = Ab + (size_t)MM * KK;
  const size_t need = 36864 + ((size_t)MM * KK + (size_t)NN * KK) * 2;
  const bool fast = ws_size >= need;

  // fold_in(key(42), p) = threefry((0,42), (0,p)) computed on host
  uint32_t fk[8][2];
  for (int p = 1; p <= 6; ++p) threefry2x32(0u, 42u, 0u, (uint32_t)p, fk[p][0], fk[p][1]);

  if (fast) {
    k_prep<<<dim3(MM + (NN * (size_t)KK) / 2048), dim3(256), 0, stream>>>(
        input, weight, nm, Ab, Wb, st);
    k_gemm<<<dim3(NN / 256, MM / 256), dim3(512), 0, stream>>>(Ab, Wb, out);
    k_epi<<<dim3((int)(TOTAL_OUT / 2048)), dim3(256), 0, stream>>>(out, nm, st, 1, 1.0f,
                                                                   fk[1][0], fk[1][1]);
  } else {
    k_rowmax<<<dim3(MM), dim3(256), 0, stream>>>(input, nm, st);
    k_retry<<<dim3(NN / 128, MM / 128), dim3(256), 0, stream>>>(
        input, weight, nm, 1.0f, out, st, 1, fk[1][0], fk[1][1]);
  }

  float red = 2.0f;
  for (int p = 2; p <= 6; ++p, red *= 2.0f) {
    k_retry<<<dim3(NN / 128, MM / 128), dim3(256), 0, stream>>>(
        input, weight, nm, red, out, st, p, fk[p][0], fk[p][1]);
  }
}